// Round 23
// baseline (74.628 us; speedup 1.0000x reference)
//
#include <hip/hip_runtime.h>
#include <hip/hip_fp16.h>

// Problem constants (from reference)
#define B_    64
#define T_    256
#define VG_   1232
#define S_    32
#define LW_   64
#define VW_   8000
#define NTAGS 8
#define NEG_  (-1e30f)
#define LP_STRIDE 34     // per (b,t): [0]=blank lp, [1..32]=gloss lp, [33]=pad
#define TILE_H 8768      // halves per LDS tile slot (>= 257*34 = 8738, 16B mult)
#define LOG2E 1.44269504088896340736f
#define LN2   0.69314718055994530942f

__device__ __forceinline__ float exp2g(float x) {
    float r; asm("v_exp_f32 %0, %1" : "=v"(r) : "v"(x)); return r;
}
__device__ __forceinline__ float log2g(float x) {
    float r; asm("v_log_f32 %0, %1" : "=v"(r) : "v"(x)); return r;
}
// Agent-scope store/load without cache-maintenance fences (sc1 path through
// the MALL coherence point; validated R9-R21: absmax 0).
__device__ __forceinline__ void st_agent(float* p, float v) {
    __hip_atomic_store(p, v, __ATOMIC_RELAXED, __HIP_MEMORY_SCOPE_AGENT);
}
__device__ __forceinline__ float ld_agent(const float* p) {
    return __hip_atomic_load(p, __ATOMIC_RELAXED, __HIP_MEMORY_SCOPE_AGENT);
}
// Whole-wave shift-up-by-1 via DPP WAVE_SHR1 (0x138): lane l gets src[l-1],
// lane 0 keeps `fill`. Pure VALU: no LDS round-trip, no lgkmcnt.
__device__ __forceinline__ float dpp_shr1(float x, float fill) {
    int r = __builtin_amdgcn_update_dpp(
        __builtin_bit_cast(int, fill), __builtin_bit_cast(int, x),
        0x138, 0xF, 0xF, false);
    return __builtin_bit_cast(float, r);
}
// One DPP row_shl<K> add step (ctrl must be a literal constant -> template).
template <int CTRL>
__device__ __forceinline__ float dpp_add(float x) {
    int s = __builtin_amdgcn_update_dpp(
        0, __builtin_bit_cast(int, x), CTRL, 0xF, 0xF, true);
    return x + __builtin_bit_cast(float, s);
}
// Wave sum to lane 0 (lanes 16/32/48 also hold it): DPP row_shl 1/2/4/8 on
// the VALU pipe + two cross-lane combines.
__device__ __forceinline__ float wave_sum_to0(float x) {
    x = dpp_add<0x101>(x);
    x = dpp_add<0x102>(x);
    x = dpp_add<0x104>(x);
    x = dpp_add<0x108>(x);
    x += __shfl_xor(x, 16, 64);
    x += __shfl_xor(x, 32, 64);
    return x;
}

// ---------------------------------------------------------------------------
// kA: booster + max-free base-2 logsumexp + gather lp at {blank, glosses}.
// Barrier-free, one wave per (b,t) row, 4 waves/block; in-pipeline float
// counts (R21). NEW: lp stored as FP16 (halves kB staging; quant error
// ~0.01 in log2 domain, trivial vs threshold). Block 0 zeroes kB's counter.
// ---------------------------------------------------------------------------
__global__ __launch_bounds__(256) void kA_booster(
    const float* __restrict__ scores, const int* __restrict__ tag_ids,
    const int* __restrict__ glosses, __half* __restrict__ lp_h,
    int* __restrict__ counter)
{
    __shared__ float tm2L[4][NTAGS];   // wave-private rows; 128 B total
    const int tid  = threadIdx.x;
    const int lane = tid & 63;
    const int wv   = tid >> 6;
    const int row  = blockIdx.x * 4 + wv;      // [0, B*T)
    const int b    = row >> 8;                 // row / T_

    if (blockIdx.x == 0 && tid == 0) *counter = 0;   // for kB (stream-ordered)

    const float* srow = scores + (size_t)row * VG_;

    // Gather index (tiny load, issued early): lane 0 -> blank(0),
    // lanes 1..32 -> glosses[b, lane-1].
    const int gidx = (lane >= 1 && lane < 33) ? glosses[b * S_ + lane - 1] : 0;

    float4 sv[5];
    int4   tv[5];
#pragma unroll
    for (int i = 0; i < 5; ++i) {
        const int idx = i * 64 + lane;
        const bool act = (i < 4) || (lane < 52);
        sv[i] = act ? ((const float4*)srow)[idx]  : make_float4(0.f, 0.f, 0.f, 0.f);
        tv[i] = act ? ((const int4*)tag_ids)[idx] : make_int4(0, 0, 0, 0);
    }
    const float gval = srow[gidx];
    const int   gtag = tag_ids[gidx];

    // Pass 1: per-tag sums AND float counts in one register pipeline.
    float sums[NTAGS], cntf[NTAGS];
#pragma unroll
    for (int n = 0; n < NTAGS; ++n) { sums[n] = 0.f; cntf[n] = 0.f; }
#pragma unroll
    for (int i = 0; i < 5; ++i) {
        const float xs[4] = {sv[i].x, sv[i].y, sv[i].z, sv[i].w};
        const int   ts[4] = {tv[i].x, tv[i].y, tv[i].z, tv[i].w};
#pragma unroll
        for (int j = 0; j < 4; ++j) {
#pragma unroll
            for (int n = 0; n < NTAGS; ++n) {
                const bool eq = (ts[j] == n);
                sums[n] += eq ? xs[j] : 0.f;
                cntf[n] += eq ? 1.0f : 0.f;
            }
        }
    }
#pragma unroll
    for (int n = 0; n < NTAGS; ++n) {
        sums[n] = wave_sum_to0(sums[n]);
        cntf[n] = wave_sum_to0(cntf[n]);
    }

    if (lane == 0) {
        cntf[0] -= 48.0f;                  // phantom-tail correction
#pragma unroll
        for (int n = 0; n < NTAGS; ++n)
            tm2L[wv][n] = (0.1f * LOG2E) * sums[n] *
                          __builtin_amdgcn_rcpf(cntf[n]);
    }
    __builtin_amdgcn_sched_barrier(0);  // pin ds_write before the ds_reads

    // Pass 2: se = sum exp2(x*LOG2E + tm2[tag])  (max-free)
    float se = 0.f;
#pragma unroll
    for (int i = 0; i < 5; ++i) {
        const float xs[4] = {sv[i].x, sv[i].y, sv[i].z, sv[i].w};
        const int   ts[4] = {tv[i].x, tv[i].y, tv[i].z, tv[i].w};
        const bool act = (i < 4) || (lane < 52);
#pragma unroll
        for (int j = 0; j < 4; ++j) {
            const float e = exp2g(fmaf(xs[j], LOG2E, tm2L[wv][ts[j]]));
            se += act ? e : 0.f;
        }
    }
    se = wave_sum_to0(se);
    const float se0 = __builtin_bit_cast(
        float, __builtin_amdgcn_readfirstlane(__builtin_bit_cast(int, se)));
    const float lse2 = log2g(se0);             // log2(sum e^x)

    // lp2 = x*LOG2E + tm2 - lse2. Store in log2 domain as FP16.
    if (lane < 33) {
        const float v = fmaf(gval, LOG2E, tm2L[wv][gtag]) - lse2;
        lp_h[(size_t)row * LP_STRIDE + lane] = __float2half(v);
    }
}

// ---------------------------------------------------------------------------
// kB: 32 blocks x 64 threads; block scans TWO batches with their chains
// interleaved in one wave (independent chains fill each other's latency
// slots — a single wave pays full instruction latency on a serial chain,
// which R15/R18 showed is kB's real cost). Tiles staged to LDS as fp16.
// Distributed NLL gather; fence-free sc1 completion (32 arrivals).
// ---------------------------------------------------------------------------
__global__ __launch_bounds__(64) void kB_ctc_nll_final(
    const __half* __restrict__ lp_h, const int* __restrict__ glosses,
    const int* __restrict__ frames_len, const int* __restrict__ glosses_len,
    const int* __restrict__ words, const float* __restrict__ words_out,
    float* __restrict__ loss_ws, float* __restrict__ nll_ws,
    int* __restrict__ counter, float* __restrict__ out)
{
    __shared__ __align__(16) unsigned short tiles[2][TILE_H];  // 34.3 KB
    const int lane = threadIdx.x;
    const int blk  = blockIdx.x;           // 0..31
    const int b0 = blk * 2, b1 = blk * 2 + 1;

    // ---- NLL gathers for both batches (issued FIRST; hide under staging) --
    float nacc0 = 0.f, nacc1 = 0.f;
    if (lane < LW_ - 1) {
        const int t0 = words[b0 * LW_ + lane + 1];
        const int t1 = words[b1 * LW_ + lane + 1];
        if (t0 != 0) nacc0 = -words_out[((size_t)b0 * LW_ + lane) * VW_ + t0];
        if (t1 != 0) nacc1 = -words_out[((size_t)b1 * LW_ + lane) * VW_ + t1];
    }

    // ---- stage both fp16 tiles: 1088 float4 each, 17/lane ----
    {
        const float4* s0 = (const float4*)(lp_h + (size_t)b0 * T_ * LP_STRIDE);
        const float4* s1 = (const float4*)(lp_h + (size_t)b1 * T_ * LP_STRIDE);
        float4* d0 = (float4*)tiles[0];
        float4* d1 = (float4*)tiles[1];
        float4 r[17];
#pragma unroll
        for (int i = 0; i < 17; ++i) r[i] = s0[i * 64 + lane];
#pragma unroll
        for (int i = 0; i < 17; ++i) d0[i * 64 + lane] = r[i];
#pragma unroll
        for (int i = 0; i < 17; ++i) r[i] = s1[i * 64 + lane];
#pragma unroll
        for (int i = 0; i < 17; ++i) d1[i * 64 + lane] = r[i];
    }
    __syncthreads();   // single wave: compiles to the needed waitcnt

    const __half* t0h = (const __half*)tiles[0];
    const __half* t1h = (const __half*)tiles[1];

    // ext[l] per chain: even -> blank, odd -> glosses[b, l>>1]
    const bool odd  = (lane & 1) != 0;
    const int  sIdx = (lane - 1) >> 1;
    bool ok2_0 = false, ok2_1 = false;
    if (odd && sIdx >= 1) {
        const int g0  = glosses[b0 * S_ + sIdx];
        const int gp0 = glosses[b0 * S_ + sIdx - 1];
        ok2_0 = (g0 != gp0) && (g0 != 0);
        const int g1  = glosses[b1 * S_ + sIdx];
        const int gp1 = glosses[b1 * S_ + sIdx - 1];
        ok2_1 = (g1 != gp1) && (g1 != 0);
    }
    const int off = odd ? (1 + sIdx) : 0;   // same column index both chains

    float al0 = NEG_, a64_0 = NEG_;
    float al1 = NEG_, a64_1 = NEG_;
    if (lane <= 1) {
        al0 = __half2float(t0h[off]);
        al1 = __half2float(t1h[off]);
    }
    const int Tlen0 = frames_len[b0];
    const int Tlen1 = frames_len[b1];

    // Dual-chain step: the two chains are independent -> ILP fills latency.
    auto STEP2 = [&](int t, float lp0, float lpB0, float lp1, float lpB1) {
        const float a1_0 = dpp_shr1(al0, NEG_);
        const float a1_1 = dpp_shr1(al1, NEG_);
        float a2_0 = dpp_shr1(a1_0, NEG_);
        float a2_1 = dpp_shr1(a1_1, NEG_);
        a2_0 = ok2_0 ? a2_0 : NEG_;
        a2_1 = ok2_1 ? a2_1 : NEG_;
        const float m3_0 = fmaxf(al0, fmaxf(a1_0, a2_0));
        const float m3_1 = fmaxf(al1, fmaxf(a1_1, a2_1));
        const float s3_0 = (exp2g(al0 - m3_0) + exp2g(a1_0 - m3_0)) + exp2g(a2_0 - m3_0);
        const float s3_1 = (exp2g(al1 - m3_1) + exp2g(a1_1 - m3_1)) + exp2g(a2_1 - m3_1);
        const float nw0 = (m3_0 + lp0) + log2g(s3_0);
        const float nw1 = (m3_1 + lp1) + log2g(s3_1);
        const float m2_0 = fmaxf(a64_0, al0);            // a63 lane-local on 63
        const float m2_1 = fmaxf(a64_1, al1);
        const float n64_0 = (m2_0 + lpB0) + log2g(exp2g(a64_0 - m2_0) + exp2g(al0 - m2_0));
        const float n64_1 = (m2_1 + lpB1) + log2g(exp2g(a64_1 - m2_1) + exp2g(al1 - m2_1));
        if (t < Tlen0) { al0 = nw0; a64_0 = n64_0; }     // uniform per chain
        if (t < Tlen1) { al1 = nw1; a64_1 = n64_1; }
    };

    // 255 steps: 63 groups of 4 + tail of 3; next group's 16 LDS u16 reads
    // issued one group ahead (converted off-chain).
    float c0[4], cB0[4], c1[4], cB1[4];
#pragma unroll
    for (int j = 0; j < 4; ++j) {
        c0[j]  = __half2float(t0h[(1 + j) * LP_STRIDE + off]);
        cB0[j] = __half2float(t0h[(1 + j) * LP_STRIDE]);
        c1[j]  = __half2float(t1h[(1 + j) * LP_STRIDE + off]);
        cB1[j] = __half2float(t1h[(1 + j) * LP_STRIDE]);
    }
    int tbase = 1;
    for (int g = 0; g < 63; ++g) {
        float n0[4], nB0[4], n1[4], nB1[4];
        const int tb2 = tbase + 4;             // last group reads pad row 256
#pragma unroll
        for (int j = 0; j < 4; ++j) {
            n0[j]  = __half2float(t0h[(tb2 + j) * LP_STRIDE + off]);
            nB0[j] = __half2float(t0h[(tb2 + j) * LP_STRIDE]);
            n1[j]  = __half2float(t1h[(tb2 + j) * LP_STRIDE + off]);
            nB1[j] = __half2float(t1h[(tb2 + j) * LP_STRIDE]);
        }
#pragma unroll
        for (int j = 0; j < 4; ++j)
            STEP2(tbase + j, c0[j], cB0[j], c1[j], cB1[j]);
#pragma unroll
        for (int j = 0; j < 4; ++j) {
            c0[j] = n0[j]; cB0[j] = nB0[j];
            c1[j] = n1[j]; cB1[j] = nB1[j];
        }
        tbase += 4;
    }
#pragma unroll
    for (int j = 0; j < 3; ++j)
        STEP2(253 + j, c0[j], cB0[j], c1[j], cB1[j]);

    // ---- finalize both chains ----
    const float a64v0 = __shfl(a64_0, 63, 64);
    const float a64v1 = __shfl(a64_1, 63, 64);
    const int i1_0 = 2 * glosses_len[b0];
    const int i1_1 = 2 * glosses_len[b1];
    const float A0_0 = __shfl(al0, i1_0 - 1, 64);
    const float A1_0 = (i1_0 >= 64) ? a64v0 : __shfl(al0, i1_0, 64);
    const float A0_1 = __shfl(al1, i1_1 - 1, 64);
    const float A1_1 = (i1_1 >= 64) ? a64v1 : __shfl(al1, i1_1, 64);
    const float mm0 = fmaxf(A0_0, A1_0);
    const float mm1 = fmaxf(A0_1, A1_1);
    float loss0 = -(mm0 + log2g(exp2g(A0_0 - mm0) + exp2g(A1_0 - mm0))) * LN2;
    float loss1 = -(mm1 + log2g(exp2g(A0_1 - mm1) + exp2g(A1_1 - mm1))) * LN2;
    if (loss0 > 1e29f) loss0 = 0.f;
    if (loss1 > 1e29f) loss1 = 0.f;

    nacc0 = wave_sum_to0(nacc0);
    nacc1 = wave_sum_to0(nacc1);
    if (lane == 0) {
        st_agent(&loss_ws[b0], loss0);     // sc1
        st_agent(&loss_ws[b1], loss1);
        st_agent(&nll_ws[b0], nacc0);
        st_agent(&nll_ws[b1], nacc1);
    }

    // ---- completion, fence-free: drain own sc1 stores, one RMW ----
    asm volatile("s_waitcnt vmcnt(0)" ::: "memory");
    int old = 0;
    if (lane == 0) old = atomicAdd(counter, 1);
    old = __shfl(old, 0, 64);
    if (old == 31) {                        // 32nd arrival
        float v = ld_agent(&loss_ws[lane]); // sc1: MALL-coherent
        float u = ld_agent(&nll_ws[lane]);
#pragma unroll
        for (int o = 32; o >= 1; o >>= 1) {
            v += __shfl_xor(v, o, 64);
            u += __shfl_xor(u, o, 64);
        }
        if (lane == 0) {
            out[0] = v + u;                 // GLOSS_W = WORD_W = 1
            out[1] = v;
            out[2] = u;
        }
    }
}

// ---------------------------------------------------------------------------
extern "C" void kernel_launch(void* const* d_in, const int* in_sizes, int n_in,
                              void* d_out, int out_size, void* d_ws, size_t ws_size,
                              hipStream_t stream) {
    const int*   glosses     = (const int*)d_in[0];
    const int*   words       = (const int*)d_in[1];
    const float* scores      = (const float*)d_in[2];
    const float* words_out   = (const float*)d_in[3];
    const int*   frames_len  = (const int*)d_in[4];
    const int*   glosses_len = (const int*)d_in[5];
    const int*   tag_ids     = (const int*)d_in[6];
    float* out = (float*)d_out;

    float*  w       = (float*)d_ws;
    int*    counter = (int*)d_ws;   // w[0]
    float*  loss_ws = w + 16;       // 64
    float*  nll_ws  = w + 96;       // 64 (per-batch NLL partials)
    __half* lp_h    = (__half*)(w + 192);   // B*T*34 halves = 1.11 MB (16B-aligned)

    kA_booster<<<(B_ * T_) / 4, 256, 0, stream>>>(scores, tag_ids, glosses,
                                                  lp_h, counter);
    kB_ctc_nll_final<<<B_ / 2, 64, 0, stream>>>(lp_h, glosses, frames_len,
                                                glosses_len, words, words_out,
                                                loss_ws, nll_ws, counter, out);
}

// Round 24
// 47.995 us; speedup vs baseline: 1.5549x; 1.5549x over previous
//
#include <hip/hip_runtime.h>

// Problem constants (from reference)
#define B_    64
#define T_    256
#define VG_   1232
#define S_    32
#define LW_   64
#define VW_   8000
#define NTAGS 8
#define NEG_  (-1e30f)
#define LP_STRIDE 34   // per (b,t): [0]=blank lp, [1..32]=gloss lp, [33]=pad
#define LOG2E 1.44269504088896340736f
#define LN2   0.69314718055994530942f

__device__ __forceinline__ float exp2g(float x) {
    float r; asm("v_exp_f32 %0, %1" : "=v"(r) : "v"(x)); return r;
}
__device__ __forceinline__ float log2g(float x) {
    float r; asm("v_log_f32 %0, %1" : "=v"(r) : "v"(x)); return r;
}
// Agent-scope store/load without cache-maintenance fences (sc1 path through
// the MALL coherence point; validated R9-R21: absmax 0).
__device__ __forceinline__ void st_agent(float* p, float v) {
    __hip_atomic_store(p, v, __ATOMIC_RELAXED, __HIP_MEMORY_SCOPE_AGENT);
}
__device__ __forceinline__ float ld_agent(const float* p) {
    return __hip_atomic_load(p, __ATOMIC_RELAXED, __HIP_MEMORY_SCOPE_AGENT);
}
// Whole-wave shift-up-by-1 via DPP WAVE_SHR1 (0x138): lane l gets src[l-1],
// lane 0 keeps `fill`. Pure VALU: no LDS round-trip, no lgkmcnt.
__device__ __forceinline__ float dpp_shr1(float x, float fill) {
    int r = __builtin_amdgcn_update_dpp(
        __builtin_bit_cast(int, fill), __builtin_bit_cast(int, x),
        0x138, 0xF, 0xF, false);
    return __builtin_bit_cast(float, r);
}
// One DPP row_shl<K> add step (ctrl must be a literal constant -> template).
template <int CTRL>
__device__ __forceinline__ float dpp_add(float x) {
    int s = __builtin_amdgcn_update_dpp(
        0, __builtin_bit_cast(int, x), CTRL, 0xF, 0xF, true);
    return x + __builtin_bit_cast(float, s);
}
// Wave sum to lane 0 (lanes 16/32/48 also hold it): DPP row_shl 1/2/4/8 on
// the VALU pipe + two cross-lane combines.
__device__ __forceinline__ float wave_sum_to0(float x) {
    x = dpp_add<0x101>(x);
    x = dpp_add<0x102>(x);
    x = dpp_add<0x104>(x);
    x = dpp_add<0x108>(x);
    x += __shfl_xor(x, 16, 64);
    x += __shfl_xor(x, 32, 64);
    return x;
}

// ---------------------------------------------------------------------------
// kA: booster + max-free base-2 logsumexp + gather lp at {blank, glosses}.
// Barrier-free, one wave per (b,t) row, 4 waves/block; in-pipeline float
// counts (R21 — no k0 kernel). fp32 lp (R23's fp16 reverted). Block 0
// zeroes kB's completion counter. lp stored in LOG2 domain.
// ---------------------------------------------------------------------------
__global__ __launch_bounds__(256) void kA_booster(
    const float* __restrict__ scores, const int* __restrict__ tag_ids,
    const int* __restrict__ glosses, float* __restrict__ lp_ws,
    int* __restrict__ counter)
{
    __shared__ float tm2L[4][NTAGS];   // wave-private rows; 128 B total
    const int tid  = threadIdx.x;
    const int lane = tid & 63;
    const int wv   = tid >> 6;
    const int row  = blockIdx.x * 4 + wv;      // [0, B*T)
    const int b    = row >> 8;                 // row / T_

    if (blockIdx.x == 0 && tid == 0) *counter = 0;   // for kB (stream-ordered)

    const float* srow = scores + (size_t)row * VG_;

    const int gidx = (lane >= 1 && lane < 33) ? glosses[b * S_ + lane - 1] : 0;

    float4 sv[5];
    int4   tv[5];
#pragma unroll
    for (int i = 0; i < 5; ++i) {
        const int idx = i * 64 + lane;
        const bool act = (i < 4) || (lane < 52);
        sv[i] = act ? ((const float4*)srow)[idx]  : make_float4(0.f, 0.f, 0.f, 0.f);
        tv[i] = act ? ((const int4*)tag_ids)[idx] : make_int4(0, 0, 0, 0);
    }
    const float gval = srow[gidx];
    const int   gtag = tag_ids[gidx];

    // Pass 1: per-tag sums AND float counts in one register pipeline.
    float sums[NTAGS], cntf[NTAGS];
#pragma unroll
    for (int n = 0; n < NTAGS; ++n) { sums[n] = 0.f; cntf[n] = 0.f; }
#pragma unroll
    for (int i = 0; i < 5; ++i) {
        const float xs[4] = {sv[i].x, sv[i].y, sv[i].z, sv[i].w};
        const int   ts[4] = {tv[i].x, tv[i].y, tv[i].z, tv[i].w};
#pragma unroll
        for (int j = 0; j < 4; ++j) {
#pragma unroll
            for (int n = 0; n < NTAGS; ++n) {
                const bool eq = (ts[j] == n);
                sums[n] += eq ? xs[j] : 0.f;
                cntf[n] += eq ? 1.0f : 0.f;
            }
        }
    }
#pragma unroll
    for (int n = 0; n < NTAGS; ++n) {
        sums[n] = wave_sum_to0(sums[n]);
        cntf[n] = wave_sum_to0(cntf[n]);
    }

    if (lane == 0) {
        cntf[0] -= 48.0f;                  // phantom-tail correction
#pragma unroll
        for (int n = 0; n < NTAGS; ++n)
            tm2L[wv][n] = (0.1f * LOG2E) * sums[n] *
                          __builtin_amdgcn_rcpf(cntf[n]);
    }
    __builtin_amdgcn_sched_barrier(0);  // pin ds_write before the ds_reads

    // Pass 2: se = sum exp2(x*LOG2E + tm2[tag])  (max-free; safe: sumexp<=~5e5)
    float se = 0.f;
#pragma unroll
    for (int i = 0; i < 5; ++i) {
        const float xs[4] = {sv[i].x, sv[i].y, sv[i].z, sv[i].w};
        const int   ts[4] = {tv[i].x, tv[i].y, tv[i].z, tv[i].w};
        const bool act = (i < 4) || (lane < 52);
#pragma unroll
        for (int j = 0; j < 4; ++j) {
            const float e = exp2g(fmaf(xs[j], LOG2E, tm2L[wv][ts[j]]));
            se += act ? e : 0.f;
        }
    }
    se = wave_sum_to0(se);
    const float se0 = __builtin_bit_cast(
        float, __builtin_amdgcn_readfirstlane(__builtin_bit_cast(int, se)));
    const float lse2 = log2g(se0);             // log2(sum e^x)

    if (lane < 33) {
        const float v = fmaf(gval, LOG2E, tm2L[wv][gtag]) - lse2;
        lp_ws[(size_t)row * LP_STRIDE + lane] = v;
    }
}

// ---------------------------------------------------------------------------
// kB scan body — STATE-SHIFTED log2 scan. Lane l holds state l+1 (of 65).
// State 0 has ONLY a self-loop (no l-1/l-2) -> its update is a plain add
// a0 += lpB (no LSE, no trans), carried as a wave-uniform scalar and fed to
// lane 0 via the DPP fill operand. This deletes the old a64 side chain
// (2 exp2 + 1 log2 + ~5 VALU per step = ~30% of the issue-bound step cost;
// R23 proved the scan is issue-bound, so issued-op count is the lever).
// Per-lane mapping: even lane l = odd (gloss) state l+1, off = 1 + (l>>1);
// odd lane = blank state, off = 0. ok2 follows the shifted states.
// ---------------------------------------------------------------------------
template <bool FULL>
__device__ __forceinline__ void scan_body(
    const float* __restrict__ tile, int lane, int off, bool ok2, int Tlen,
    float& alpha, float& a0c)
{
    auto STEP = [&](int t, float lp, float lpB) {
        const float a1 = dpp_shr1(alpha, a0c);           // lane0 <- state 0
        float a2 = dpp_shr1(a1, NEG_);                   // lane1 <- state 0
        a2 = ok2 ? a2 : NEG_;                            // lane0 masked (ok2=0)
        const float m3 = fmaxf(alpha, fmaxf(a1, a2));    // v_max3
        const float e0 = exp2g(alpha - m3);
        const float e1 = exp2g(a1 - m3);
        const float e2 = exp2g(a2 - m3);
        const float nw = (m3 + lp) + log2g((e0 + e1) + e2);
        const float n0 = a0c + lpB;                      // state-0 chain: 1 add
        if (FULL || t < Tlen) { alpha = nw; a0c = n0; }  // uniform
    };

    float cur[4], curB[4];
#pragma unroll
    for (int j = 0; j < 4; ++j) {
        cur[j]  = tile[(1 + j) * LP_STRIDE + off];
        curB[j] = tile[(1 + j) * LP_STRIDE];
    }
    int tbase = 1;
    for (int g = 0; g < 63; ++g) {
        float nxt[4], nxtB[4];
        const int tb2 = tbase + 4;             // last group reads pad row 256
#pragma unroll
        for (int j = 0; j < 4; ++j) {
            nxt[j]  = tile[(tb2 + j) * LP_STRIDE + off];
            nxtB[j] = tile[(tb2 + j) * LP_STRIDE];
        }
#pragma unroll
        for (int j = 0; j < 4; ++j) STEP(tbase + j, cur[j], curB[j]);
#pragma unroll
        for (int j = 0; j < 4; ++j) { cur[j] = nxt[j]; curB[j] = nxtB[j]; }
        tbase += 4;
    }
#pragma unroll
    for (int j = 0; j < 3; ++j) STEP(253 + j, cur[j], curB[j]);
}

// ---------------------------------------------------------------------------
// kB: 64 blocks, one per batch (R14 structure). Distributed NLL gather,
// LDS-staged state-shifted scan, fence-free completion.
// ---------------------------------------------------------------------------
__global__ __launch_bounds__(256) void kB_ctc_nll_final(
    const float* __restrict__ lp_ws, const int* __restrict__ glosses,
    const int* __restrict__ frames_len, const int* __restrict__ glosses_len,
    const int* __restrict__ words, const float* __restrict__ words_out,
    float* __restrict__ loss_ws, float* __restrict__ nll_ws,
    int* __restrict__ counter, float* __restrict__ out)
{
    __shared__ __align__(16) float tile[(T_ + 1) * LP_STRIDE];  // +pad row
    const int tid = threadIdx.x;
    const int b   = blockIdx.x;

    // ---- NLL gather for this batch (issued FIRST; hides under staging) ----
    float nacc = 0.f;
    if (tid < LW_ - 1) {
        const int tgt = words[b * LW_ + tid + 1];
        if (tgt != 0)
            nacc = -words_out[((size_t)b * LW_ + tid) * VW_ + tgt];
    }

    // ---- stage lp tile: 8704 floats = 2176 float4, 256 threads ----
    {
        const float4* src4 = (const float4*)(lp_ws + (size_t)b * T_ * LP_STRIDE);
        float4* dst4 = (float4*)tile;
        float4 r[9];
#pragma unroll
        for (int i = 0; i < 9; ++i) {
            const int idx = i * 256 + tid;
            if (idx < 2176) r[i] = src4[idx];
        }
#pragma unroll
        for (int i = 0; i < 9; ++i) {
            const int idx = i * 256 + tid;
            if (idx < 2176) dst4[idx] = r[i];
        }
    }
    __syncthreads();
    if (tid >= 64) return;                 // scan is single-wave
    const int lane = tid;

    // Lane l = state l+1. Even lane -> odd (gloss) state, sIdx = l>>1;
    // odd lane -> even (blank) state.
    const bool glossState = (lane & 1) == 0;
    const int  sIdx = lane >> 1;           // valid when glossState
    bool ok2 = false;                      // l-2 skip path permitted?
    if (glossState && sIdx >= 1) {
        const int g  = glosses[b * S_ + sIdx];
        const int gp = glosses[b * S_ + sIdx - 1];
        ok2 = (g != gp) && (g != 0);
    }
    const int off = glossState ? (1 + sIdx) : 0;   // column in 34-wide row

    // Init: state 1 (lane 0) = lp0[gloss0]; others dead. State 0 = lp0[blank].
    float alpha = (lane == 0) ? tile[off] : NEG_;
    float a0c   = tile[0];
    const int Tlen = frames_len[b];

    if (Tlen == T_) scan_body<true >(tile, lane, off, ok2, Tlen, alpha, a0c);
    else            scan_body<false>(tile, lane, off, ok2, Tlen, alpha, a0c);

    // Readout: states i0 = 2*len-1, i1 = 2*len  ->  lanes i1-2, i1-1.
    const int i1 = 2 * glosses_len[b];     // in [2, 64]
    const float A0 = __shfl(alpha, i1 - 2, 64);
    const float A1 = __shfl(alpha, i1 - 1, 64);
    const float mm = fmaxf(A0, A1);
    float loss = -(mm + log2g(exp2g(A0 - mm) + exp2g(A1 - mm))) * LN2;
    if (loss > 1e29f) loss = 0.f;

    // NLL partial: lanes 0..62 hold gathers (lane 63 = 0); fixed-order sum.
    nacc = wave_sum_to0(nacc);
    if (lane == 0) {
        st_agent(&loss_ws[b], loss);       // sc1
        st_agent(&nll_ws[b], nacc);        // sc1
    }

    // ---- completion, fence-free: drain own sc1 stores, one RMW ----
    asm volatile("s_waitcnt vmcnt(0)" ::: "memory");
    int old = 0;
    if (lane == 0) old = atomicAdd(counter, 1);
    old = __shfl(old, 0, 64);
    if (old == B_ - 1) {                   // 64th arrival
        float v = ld_agent(&loss_ws[lane]); // sc1: MALL-coherent
        float u = ld_agent(&nll_ws[lane]);
#pragma unroll
        for (int o = 32; o >= 1; o >>= 1) {
            v += __shfl_xor(v, o, 64);
            u += __shfl_xor(u, o, 64);
        }
        if (lane == 0) {
            out[0] = v + u;                // GLOSS_W = WORD_W = 1
            out[1] = v;
            out[2] = u;
        }
    }
}

// ---------------------------------------------------------------------------
extern "C" void kernel_launch(void* const* d_in, const int* in_sizes, int n_in,
                              void* d_out, int out_size, void* d_ws, size_t ws_size,
                              hipStream_t stream) {
    const int*   glosses     = (const int*)d_in[0];
    const int*   words       = (const int*)d_in[1];
    const float* scores      = (const float*)d_in[2];
    const float* words_out   = (const float*)d_in[3];
    const int*   frames_len  = (const int*)d_in[4];
    const int*   glosses_len = (const int*)d_in[5];
    const int*   tag_ids     = (const int*)d_in[6];
    float* out = (float*)d_out;

    float* w       = (float*)d_ws;
    int*   counter = (int*)d_ws;   // w[0]
    float* loss_ws = w + 16;       // 64
    float* nll_ws  = w + 96;       // 64 (per-batch NLL partials)
    float* lp_ws   = w + 192;      // B*T*34 floats = 2.23 MB (16B-aligned)

    kA_booster<<<(B_ * T_) / 4, 256, 0, stream>>>(scores, tag_ids, glosses,
                                                  lp_ws, counter);
    kB_ctc_nll_final<<<B_, 256, 0, stream>>>(lp_ws, glosses, frames_len,
                                             glosses_len, words, words_out,
                                             loss_ws, nll_ws, counter, out);
}